// Round 16
// baseline (149.419 us; speedup 1.0000x reference)
//
#include <hip/hip_runtime.h>
#include <cstdint>
#include <cstddef>

#define J 64
#define XD 512
#define HD 1024
#define YD 16
#define PP 8
#define NN 1024

typedef __bf16 bf16;
typedef __attribute__((ext_vector_type(8))) __bf16 bf16x8;
typedef __attribute__((ext_vector_type(4))) __bf16 bf16x4;
typedef __attribute__((ext_vector_type(4))) float f32x4;

__device__ __forceinline__ void gload16(const void* g, void* l) {
  __builtin_amdgcn_global_load_lds((__attribute__((address_space(1))) void*)(g),
                                   (__attribute__((address_space(3))) void*)(l),
                                   16, 0, 0);
}

// ---- K1 (merged): blocks [0,8192) build W1T; blocks [8192,14596) build the rest.
__global__ __launch_bounds__(256) void build_all(
    const float* __restrict__ muW1, const float* __restrict__ sigW1,
    const float* __restrict__ eW1, bf16* __restrict__ W1T,
    const float* __restrict__ x,
    const float* __restrict__ muW2, const float* __restrict__ sigW2,
    const float* __restrict__ eW2,
    const float* __restrict__ mub1, const float* __restrict__ sigb1,
    const float* __restrict__ eb1,
    const float* __restrict__ mub2, const float* __restrict__ sigb2,
    const float* __restrict__ eb2,
    bf16* __restrict__ XBF, bf16* __restrict__ W2T,
    float* __restrict__ B1W, float* __restrict__ B2W) {
  __shared__ bf16 sT[64][66];  // used only by the W1T path
  int b = blockIdx.x;
  int tid = threadIdx.x;
  if (b < 8192) {
    int j = b >> 7;
    int xt = (b >> 4) & 7;
    int ht = b & 15;
    int x0 = xt << 6, h0 = ht << 6;
    int rp = tid >> 4;
    int cp = (tid & 15) << 2;
    const float* eB = eW1 + (size_t)j * (XD * HD);
#pragma unroll
    for (int p = 0; p < 4; ++p) {
      int xx = rp + (p << 4);
      size_t gi = (size_t)(x0 + xx) * HD + (h0 + cp);
      f32x4 e = *(const f32x4*)(eB + gi);
      f32x4 m = *(const f32x4*)(muW1 + gi);
      f32x4 s = *(const f32x4*)(sigW1 + gi);
#pragma unroll
      for (int i = 0; i < 4; ++i) sT[cp + i][xx] = (bf16)(m[i] + e[i] * s[i]);
    }
    __syncthreads();
#pragma unroll
    for (int p = 0; p < 4; ++p) {
      int h = rp + (p << 4);
      bf16x4 v;
#pragma unroll
      for (int i = 0; i < 4; ++i) v[i] = sT[h][cp + i];
      *(bf16x4*)(W1T + (size_t)(j * HD + h0 + h) * XD + (x0 + cp)) = v;
    }
    return;
  }
  int i = (b - 8192) * 256 + tid;
  const int c0 = NN * XD;
  const int c1 = J * YD * HD;
  const int c2 = J * HD;
  const int c3 = J * YD;
  if (i < c0) { XBF[i] = (bf16)x[i]; return; }
  i -= c0;
  if (i < c1) {
    int h = i & (HD - 1);
    int jy = i >> 10;
    int y = jy & 15;
    int j = jy >> 4;
    float mu = muW2[h * YD + y], sg = sigW2[h * YD + y];
    float e = eW2[((size_t)j * HD + h) * YD + y];
    W2T[i] = (bf16)(mu + e * sg);
    return;
  }
  i -= c1;
  if (i < c2) {
    int h = i & (HD - 1);
    B1W[i] = mub1[h] + eb1[i] * sigb1[h];
    return;
  }
  i -= c2;
  if (i < c3) {
    int y = i & 15;
    B2W[i] = mub2[y] + eb2[i] * sigb2[y];
  }
}

// ---- K2: fused GEMM1 + clip + GEMM2 + permutation scatter
// grid 512 (64 j x 8 n-tiles of 128), 256 threads / 4 waves (2n x 2h),
// block tile 128n x 256h, wave tile 64n x 128h (intensity 21.3 MACs/B).
// acc1[8][4]=128 f32 in VGPRs: 256-thread workgroup gets 240-VGPR budget
// (R12 measured), peak demand ~210 -> no spill.
// LDS = 64KB EXACTLY -> 2 blocks/CU (R2-proven at 64KB): 2 waves/SIMD from
// INDEPENDENT blocks -> one block's barrier/drain bubbles fill with the other's
// MFMA (R15's same-block lockstep left 44%/step idle).
// BK=32, paired-row layout (R14-proven): 2 logical 64B rows per 128B LDS row,
// slot_log = ((row&1)<<2)|kchunk, phys = slot_log ^ (pairrow&7).
// LDS: sA dbuf 2x8KB @0, sB dbuf 2x16KB @16384, sH [128n][64h] 16KB @49152
__global__ __launch_bounds__(256)
void fused_mlp(
    const bf16* __restrict__ XBF, const bf16* __restrict__ W1T,
    const bf16* __restrict__ W2T, const float* __restrict__ B1W,
    const float* __restrict__ B2W, const float* __restrict__ permu,
    float* __restrict__ out) {
  extern __shared__ char smem[];          // 65536 bytes

  int bid = blockIdx.x;
  // XCD swizzle: XCD x gets j in [8x,8x+8), all 8 n-tiles of each j together
  int L = ((bid & 7) << 6) | (bid >> 3);
  int j = L >> 3;
  int n0 = (L & 7) << 7;

  int tid = threadIdx.x;
  int wid = tid >> 6;               // 0..3
  int lane = tid & 63;
  int l15 = lane & 15;
  int lg = lane >> 4;               // 0..3
  int wn2 = (wid & 1) << 6;         // wave n offset (0,64)
  int wh2 = (wid >> 1) << 7;        // wave h offset (0,128) in the 256h panel

  const bf16* w1base = W1T + (size_t)j * (HD * XD);
  const bf16* w2g = W2T + (size_t)((j << 4) + l15) * HD;  // row y = l15
  bf16* sH = (bf16*)(smem + 49152);

  f32x4 acc2[2];
#pragma unroll
  for (int f = 0; f < 2; ++f)
#pragma unroll
    for (int r = 0; r < 4; ++r) acc2[f][r] = 0.0f;

  // stage (BK=32): sA = x rows [n0,n0+128), sB = W1T rows [hb*256,+256)
  auto stage = [&](int d, int k0, int hb_) {
#pragma unroll
    for (int q = 0; q < 2; ++q) {         // sA 8KB
      int doff = (q << 12) + (tid << 4);
      int pr = doff >> 7;
      int sl = ((doff >> 4) & 7) ^ (pr & 7);
      int n = (pr << 1) | (sl >> 2);
      int kc = sl & 3;
      gload16(XBF + (size_t)(n0 + n) * XD + k0 + (kc << 3),
              smem + d * 8192 + doff);
    }
#pragma unroll
    for (int q = 0; q < 4; ++q) {         // sB 16KB
      int doff = (q << 12) + (tid << 4);
      int pr = doff >> 7;
      int sl = ((doff >> 4) & 7) ^ (pr & 7);
      int h = (pr << 1) | (sl >> 2);
      int kc = sl & 3;
      gload16(w1base + (size_t)((hb_ << 8) + h) * XD + k0 + (kc << 3),
              smem + 16384 + d * 16384 + doff);
    }
  };

  // prologue
  stage(0, 0, 0);
  asm volatile("s_waitcnt vmcnt(0)" ::: "memory");
  __builtin_amdgcn_s_barrier();

#pragma unroll 1
  for (int hb = 0; hb < 4; ++hb) {
    // acc1[fb][fa]: fb = h frag (wave's 128h), fa = n frag (wave's 64n)
    f32x4 acc1[8][4];
#pragma unroll
    for (int fb = 0; fb < 8; ++fb)
#pragma unroll
      for (int fa = 0; fa < 4; ++fa)
#pragma unroll
        for (int r = 0; r < 4; ++r) acc1[fb][fa][r] = 0.0f;

#pragma unroll 1
    for (int t = 0; t < 16; ++t) {
      int cur = ((hb << 4) + t) & 1;
      const char* a_d = smem + cur * 8192;
      const char* b_d = smem + 16384 + cur * 16384;
      bf16x8 af[4], bg[8];
#pragma unroll
      for (int fa = 0; fa < 4; ++fa) {
        int ra = wn2 + (fa << 4) + l15;
        int pr = ra >> 1;
        int ph = (((ra & 1) << 2) | lg) ^ (pr & 7);
        af[fa] = *(const bf16x8*)(a_d + (pr << 7) + (ph << 4));
      }
#pragma unroll
      for (int fb = 0; fb < 8; ++fb) {
        int rb = wh2 + (fb << 4) + l15;
        int pr = rb >> 1;
        int ph = (((rb & 1) << 2) | lg) ^ (pr & 7);
        bg[fb] = *(const bf16x8*)(b_d + (pr << 7) + (ph << 4));
      }
      // stage issue after the reads, before the MFMA cluster (R15-proven order)
      if (t < 15)           stage(cur ^ 1, (t + 1) << 5, hb);
      else if (hb < 3)      stage(cur ^ 1, 0, hb + 1);
      __builtin_amdgcn_s_setprio(1);
#pragma unroll
      for (int fb = 0; fb < 8; ++fb)
#pragma unroll
        for (int fa = 0; fa < 4; ++fa)
          acc1[fb][fa] = __builtin_amdgcn_mfma_f32_16x16x32_bf16(
              bg[fb], af[fa], acc1[fb][fa], 0, 0, 0);  // A=W1(h), B=x(n)
      __builtin_amdgcn_s_setprio(0);
      asm volatile("s_waitcnt vmcnt(0)" ::: "memory");
      __builtin_amdgcn_s_barrier();
    }

    // b1 for this wave's 128-h slice (D rows = lg*4+r)
    f32x4 b1v[8];
#pragma unroll
    for (int fb = 0; fb < 8; ++fb)
      b1v[fb] = *(const f32x4*)&B1W[(j << 10) + (hb << 8) + wh2 + (fb << 4) + (lg << 2)];

    // ---- 4 h-chunks of 64 (FULLY UNROLLED: acc1 index must be compile-time)
#pragma unroll
    for (int c = 0; c < 4; ++c) {
      __builtin_amdgcn_s_barrier();   // prev chunk's GEMM2 reads done
      bf16x8 wg[2];
#pragma unroll
      for (int k2 = 0; k2 < 2; ++k2)
        wg[k2] = *(const bf16x8*)(w2g + (hb << 8) + (c << 6) + (k2 << 5) + (lg << 3));
      if ((wid >> 1) == (c >> 1)) {   // the two n-waves of this h-half write
#pragma unroll
        for (int fa = 0; fa < 4; ++fa)
#pragma unroll
          for (int q = 0; q < 4; ++q) {
            int fb = ((c & 1) << 2) + q;
            bf16x4 pk;
#pragma unroll
            for (int r = 0; r < 4; ++r) {
              float v = acc1[fb][fa][r] + b1v[fb][r];
              v = fminf(1.0f, fmaxf(-1.0f, v));
              pk[r] = (bf16)v;
            }
            int n = wn2 + (fa << 4) + l15;
            int hl = (q << 4) + (lg << 2);          // chunk-local h 0..63
            int byte = (n << 7) + ((hl << 1) ^ ((n & 7) << 4));
            *(bf16x4*)((char*)sH + byte) = pk;
          }
      }
      asm volatile("s_waitcnt lgkmcnt(0)" ::: "memory");
      __builtin_amdgcn_s_barrier();   // sH chunk visible
      // GEMM2: wave owns rows wid*32..+32 of 128
#pragma unroll
      for (int k2 = 0; k2 < 2; ++k2) {
#pragma unroll
        for (int f = 0; f < 2; ++f) {
          int row = (wid << 5) + (f << 4) + l15;
          int cb = ((k2 << 6) + (lg << 4)) ^ ((row & 7) << 4);
          bf16x8 hf = *(const bf16x8*)((char*)sH + (row << 7) + cb);
          acc2[f] = __builtin_amdgcn_mfma_f32_16x16x32_bf16(hf, wg[k2], acc2[f], 0, 0, 0);
        }
      }
    }
  }

  // ---- epilogue: b2, stage out tile (reuses sA region), permutation gather
  float b2v = B2W[(j << 4) + l15];
  float* sOut = (float*)smem;              // [128][17] f32 = 8704B
  int* sIdx = (int*)(smem + 12288);        // [128]
#pragma unroll
  for (int f = 0; f < 2; ++f)
#pragma unroll
    for (int r = 0; r < 4; ++r) {
      int row = (wid << 5) + (f << 4) + (lg << 2) + r;
      sOut[row * 17 + l15] = acc2[f][r] + b2v;
    }
  if (tid < 128) {  // cidx[p][y] = col c with permu[p][c][y]==1
    int p = tid >> 4, y = tid & 15;
    int c = 0;
#pragma unroll
    for (int cc = 0; cc < 16; ++cc)
      if (permu[((p << 4) + cc) * 16 + y] > 0.5f) c = cc;
    sIdx[tid] = c;
  }
  __syncthreads();
#pragma unroll 1
  for (int it = 0; it < 16; ++it) {
    int flat = (it << 10) + (tid << 2);   // p[3] n[7] y[4]
    int p = flat >> 11;
    int n = (flat >> 4) & 127;
    int y0 = flat & 15;
    f32x4 v;
#pragma unroll
    for (int q = 0; q < 4; ++q) v[q] = sOut[n * 17 + sIdx[(p << 4) + y0 + q]];
    *(f32x4*)(out + ((size_t)((j << 3) + p) * NN + n0 + n) * YD + y0) = v;
  }
}

extern "C" void kernel_launch(void* const* d_in, const int* in_sizes, int n_in,
                              void* d_out, int out_size, void* d_ws, size_t ws_size,
                              hipStream_t stream) {
  (void)in_sizes; (void)n_in; (void)out_size; (void)ws_size;
  const float* x      = (const float*)d_in[0];
  const float* mu_W1  = (const float*)d_in[1];
  const float* mu_b1  = (const float*)d_in[2];
  const float* mu_W2  = (const float*)d_in[3];
  const float* mu_b2  = (const float*)d_in[4];
  const float* sig_W1 = (const float*)d_in[5];
  const float* sig_b1 = (const float*)d_in[6];
  const float* sig_W2 = (const float*)d_in[7];
  const float* sig_b2 = (const float*)d_in[8];
  const float* e_W1   = (const float*)d_in[9];
  const float* e_b1   = (const float*)d_in[10];
  const float* e_W2   = (const float*)d_in[11];
  const float* e_b2   = (const float*)d_in[12];
  const float* permu  = (const float*)d_in[13];
  float* out = (float*)d_out;

  char* ws = (char*)d_ws;
  bf16* W1T = (bf16*)(ws);
  bf16* W2T = (bf16*)(ws + 67108864);
  bf16* XBF = (bf16*)(ws + 69206016);
  float* B1W = (float*)(ws + 70254592);
  float* B2W = (float*)(ws + 70516736);

  build_all<<<dim3(14596), dim3(256), 0, stream>>>(
      mu_W1, sig_W1, e_W1, W1T,
      x, mu_W2, sig_W2, e_W2, mu_b1, sig_b1, e_b1, mu_b2, sig_b2, e_b2,
      XBF, W2T, B1W, B2W);
  fused_mlp<<<dim3(512), dim3(256), 65536, stream>>>(
      XBF, W1T, W2T, B1W, B2W, permu, out);
}